// Round 8
// baseline (860.721 us; speedup 1.0000x reference)
//
#include <hip/hip_runtime.h>

// Problem constants
#define NB    2048   // n_back (k), innermost dim of w tensors
#define NOUT  2048   // H*W*COUT
#define NDIM  2048   // H*W*CIN

// Output flat offsets (floats) in d_out: [w_u_, b_u_, w_l_, b_l_]
#define OFF_BU  16777216ull
#define OFF_WL  16785408ull
#define OFF_BL  33562624ull

// ws layout (floats): [0,16384) bias partials (2,4,2048); [16384,16960) T
#define WS_T    16384

typedef float f32x2 __attribute__((ext_vector_type(2)));

// T[((co*8+ci)*3+kh)*3+kw] = kern[((kh*3+kw)*8+ci)*8+co]
// -> per co, all 72 weights are CONTIGUOUS: enables s_load_dwordx8/x16.
__global__ void prep_kernel(const float* __restrict__ kern, float* __restrict__ T) {
    const int i = blockIdx.x * 64 + threadIdx.x;   // 0..575
    if (i < 576) {
        const int kw = i % 3, kh = (i / 3) % 3, ci = (i / 9) % 8, co = i / 72;
        T[i] = kern[((kh * 3 + kw) * 8 + ci) * 8 + co];
    }
}

// Rolling-window conv-backward, take 2.
// Thread: f32x2 over k, ONE wi, all 8 ci, 8 output rows (rolling 3-row acc).
// Block: 256 thr = 4 waves = 4 adjacent wi (wave-uniform wi). Full #pragma
// unroll over the 10 in-rows: acc rotation becomes SSA renaming; T loads
// become wide scalar loads CSE'd/scheduled through straight-line code.
// In-row ho feeds out rows ho-1 (kh=0, a0), ho (kh=1, a1), ho+1 (kh=2, a2).
__global__ __launch_bounds__(256, 4) void conv_back_kernel(
    const float* __restrict__ wu,
    const float* __restrict__ wl,
    const float* __restrict__ Tw,     // (8co,8ci,3,3) transposed weights
    const float* __restrict__ bias,   // (8)
    float* __restrict__ outbuf,       // full d_out base
    float* __restrict__ bias_ws)      // (2,4,2048) partial bias sums
{
    const int bid   = blockIdx.x;            // 0..1023
    const int wig   = bid >> 8;              // 0..3  (wi group; +256 apart -> same XCD for seam reuse)
    const int rem   = bid & 255;
    const int slice = rem >> 5;              // 0..7 (t,b)
    const int hh    = (rem >> 4) & 1;        // hi half
    const int kc    = rem & 15;              // k chunk (128 floats)
    const int t = slice >> 2, b = slice & 3;
    const int kl  = threadIdx.x & 63;
    const int sub = threadIdx.x >> 6;        // 0..3
    const int wi  = wig * 4 + sub;           // 0..15, wave-uniform
    const int r0  = hh * 8;                  // first owned out row
    const int k2  = kc * 64 + kl;            // f32x2 index over k, 0..1023

    const f32x2* __restrict__ in = (const f32x2*)(t ? wl : wu) + (size_t)b * NOUT * 1024 + k2;
    f32x2* __restrict__ wout = (f32x2*)(outbuf + (t ? OFF_WL : 0)) + (size_t)b * NDIM * 1024 + k2;

    const bool vlo = wi > 0;                 // wave-uniform edge masks
    const bool vhi = wi < 15;

    f32x2 a0[8], a1[8], a2[8];               // out rows ho-1 / ho / ho+1
    #pragma unroll
    for (int ci = 0; ci < 8; ++ci) { a0[ci] = (f32x2)(0.f); a1[ci] = (f32x2)(0.f); a2[ci] = (f32x2)(0.f); }
    f32x2 pb = (f32x2)(0.f);

    #pragma unroll
    for (int s = 0; s < 10; ++s) {
        const int ho = r0 - 1 + s;           // current in-row
        if ((unsigned)ho < 16u) {            // runtime-uniform only for s=0,9
            const f32x2* rowb = in + (size_t)(ho * 16 * 8) * 1024;
            #pragma unroll
            for (int co = 0; co < 8; ++co) {
                // u3[j] = in col (wi-1+j), this co
                f32x2 u3[3];
                u3[0] = vlo ? rowb[(size_t)((wi - 1) * 8 + co) * 1024] : (f32x2)(0.f);
                u3[1] = rowb[(size_t)(wi * 8 + co) * 1024];
                u3[2] = vhi ? rowb[(size_t)((wi + 1) * 8 + co) * 1024] : (f32x2)(0.f);

                if (s >= 1 && s <= 8)        // ho is an owned row
                    pb += bias[co] * u3[1];

                const float* tb = Tw + co * 72;   // 72 contiguous weights
                #pragma unroll
                for (int ci = 0; ci < 8; ++ci) {
                    #pragma unroll
                    for (int kw = 0; kw < 3; ++kw) {
                        // weight K[kh,kw,ci,co] x u[wi+1-kw]  (dw = 1-kw)
                        a0[ci] += tb[ci * 9 + 0 * 3 + kw] * u3[2 - kw];
                        a1[ci] += tb[ci * 9 + 1 * 3 + kw] * u3[2 - kw];
                        a2[ci] += tb[ci * 9 + 2 * 3 + kw] * u3[2 - kw];
                    }
                }
            }
        }

        if (s >= 2) {                        // out row r = ho-1 is complete
            const int r = r0 + s - 2;        // r0 .. r0+7
            #pragma unroll
            for (int ci = 0; ci < 8; ++ci)
                wout[(size_t)((r * 16 + wi) * 8 + ci) * 1024] = a0[ci];
        }

        // rotate (SSA-renamed away by full unroll)
        #pragma unroll
        for (int ci = 0; ci < 8; ++ci) { a0[ci] = a1[ci]; a1[ci] = a2[ci]; a2[ci] = (f32x2)(0.f); }
    }

    // reduce bias partials across the 4 sub-waves (same k2, different wi)
    __shared__ f32x2 red[4][64];
    red[sub][kl] = pb;
    __syncthreads();
    if (sub == 0) {
        f32x2 tot = red[0][kl] + red[1][kl] + red[2][kl] + red[3][kl];
        float* bws = bias_ws + t * 8192 + b * 2048 + 2 * k2;
        atomicAdd(bws + 0, tot.x);
        atomicAdd(bws + 1, tot.y);
    }
}

// b_out_ = b_in + ws ; 16384 outputs (2 ul * 4 b * 2048 k)
__global__ void bias_finalize(const float* __restrict__ bu,
                              const float* __restrict__ bl,
                              const float* __restrict__ ws,
                              float* __restrict__ out)
{
    const int idx = blockIdx.x * blockDim.x + threadIdx.x;   // 0..16383
    const int ul  = idx >> 13;
    const int r   = idx & 8191;                              // b*2048 + k
    const float* bin = ul ? bl : bu;
    const size_t off = ul ? OFF_BL : OFF_BU;
    out[off + r] = bin[r] + ws[(size_t)ul * 8192 + r];
}

extern "C" void kernel_launch(void* const* d_in, const int* in_sizes, int n_in,
                              void* d_out, int out_size, void* d_ws, size_t ws_size,
                              hipStream_t stream) {
    // inputs: 0=x (unused), 1=kernel, 2=bias, 3=w_out_u, 4=b_out_u, 5=w_out_l, 6=b_out_l
    const float* kern = (const float*)d_in[1];
    const float* bias = (const float*)d_in[2];
    const float* wu   = (const float*)d_in[3];
    const float* bu   = (const float*)d_in[4];
    const float* wl   = (const float*)d_in[5];
    const float* bl   = (const float*)d_in[6];
    float* out = (float*)d_out;
    float* ws  = (float*)d_ws;

    // zero the 64 KB bias-partial region (graph replays re-run this node)
    (void)hipMemsetAsync(ws, 0, 2ull * 4 * NB * sizeof(float), stream);

    prep_kernel<<<9, 64, 0, stream>>>(kern, ws + WS_T);
    conv_back_kernel<<<dim3(1024), dim3(256), 0, stream>>>(wu, wl, ws + WS_T, bias, out, ws);
    bias_finalize<<<64, 256, 0, stream>>>(bu, bl, ws, out);
}

// Round 9
// 703.781 us; speedup vs baseline: 1.2230x; 1.2230x over previous
//
#include <hip/hip_runtime.h>

// Problem constants
#define NB    2048   // n_back (k)
#define NB2   1024   // NB/2 in f32x2 units
#define NOUT  2048   // H*W*COUT
#define NDIM  2048   // H*W*CIN

// Output flat offsets (floats) in d_out: [w_u_, b_u_, w_l_, b_l_]
#define OFF_BU  16777216ull
#define OFF_WL  16785408ull
#define OFF_BL  33562624ull

// ws layout (floats): [0,16384) bias partials (2,4,2048); [16384,16960) T
#define WS_T    16384

typedef float f32x2 __attribute__((ext_vector_type(2)));
typedef float f32x4 __attribute__((ext_vector_type(4)));

// T[co*72 + ci*9 + kh*3 + kw] = kern[((kh*3+kw)*8+ci)*8+co]
// -> per co, 72 contiguous floats (18 aligned f32x4).
__global__ void prep_kernel(const float* __restrict__ kern, float* __restrict__ T) {
    const int i = blockIdx.x * 64 + threadIdx.x;   // 0..575
    if (i < 576) {
        const int kw = i % 3, kh = (i / 3) % 3, ci = (i / 9) % 8, co = i / 72;
        T[i] = kern[((kh * 3 + kw) * 8 + ci) * 8 + co];
    }
}

// co-outer rolling conv-backward.
// Thread: f32x2 over k, one wi, 8 ci, 4 output rows (acc[4][8] = 64 VGPR).
// Outer co loop is FORCED rolled (#pragma unroll 1) so only one co's 72
// weights (18 f32x4 from LDS, wave-uniform broadcast reads) are live at a
// time -> live set ~155 VGPR, no spills (round-8 lesson: full unroll
// spilled ~2GB of scratch traffic).
// In-row ho = r0-1+s (s=0..5) feeds owned rows m = s-2+kh in [0,3]
// (compile-time per (s,kh)). Input element loaded once per wave.
// Grid: linear bid & 7 = k-low-bits -> XCD partition is k-disjoint (zero
// cross-XCD input sharing); per-XCD order walks khi,wig,hq,slice so
// wi-seam / hq-halo partner blocks are temporally adjacent on one XCD.
__global__ __launch_bounds__(256, 3) void conv_back_kernel(
    const float* __restrict__ wu,
    const float* __restrict__ wl,
    const float* __restrict__ Tw,     // (8co, 72) transposed weights
    const float* __restrict__ bias,   // (8)
    float* __restrict__ outbuf,       // full d_out base
    float* __restrict__ bias_ws)      // (2,4,2048) partial bias sums
{
    const int bid = blockIdx.x;            // 0..2047
    const int klo = bid & 7;               // XCD id
    const int j   = bid >> 3;              // per-XCD order
    const int khi = j & 1;
    const int wig = (j >> 1) & 3;
    const int hq  = (j >> 3) & 3;
    const int sl  = j >> 5;                // 0..7
    const int t = sl >> 2, b = sl & 3;
    const int kc  = khi * 8 + klo;         // k chunk 0..15 (128 floats each)
    const int kl  = threadIdx.x & 63;
    const int sub = threadIdx.x >> 6;      // 0..3
    const int wi  = wig * 4 + sub;         // 0..15, wave-uniform
    const int r0  = hq * 4;                // first owned out row
    const int k2  = kc * 64 + kl;          // f32x2 index over k, 0..1023

    __shared__ __align__(16) float Tlds[576];
    __shared__ f32x2 red[4][64];
    for (int i = threadIdx.x; i < 576; i += 256) Tlds[i] = Tw[i];
    __syncthreads();

    const f32x2* __restrict__ in =
        (const f32x2*)(t ? wl : wu) + (size_t)b * NOUT * NB2 + k2;
    f32x2* __restrict__ wout =
        (f32x2*)(outbuf + (t ? OFF_WL : 0)) + (size_t)b * NDIM * NB2 + k2;

    const bool vlo = wi > 0;               // wave-uniform edge masks
    const bool vhi = wi < 15;

    f32x2 acc[4][8];
    #pragma unroll
    for (int m = 0; m < 4; ++m)
        #pragma unroll
        for (int ci = 0; ci < 8; ++ci) acc[m][ci] = (f32x2)(0.f);
    f32x2 pb = (f32x2)(0.f);

    #pragma unroll 1
    for (int co = 0; co < 8; ++co) {
        // this co's 72 weights: 18 wave-uniform ds_read_b128 -> 72 VGPR
        f32x4 w[18];
        const f32x4* wsrc = (const f32x4*)(Tlds + co * 72);
        #pragma unroll
        for (int i = 0; i < 18; ++i) w[i] = wsrc[i];
        const float bco = bias[co];

        #pragma unroll
        for (int s = 0; s < 6; ++s) {
            const int ho = r0 - 1 + s;     // current in-row
            if ((unsigned)ho < 16u) {      // block-uniform (edges of hq 0/3)
                f32x2 u3[3];               // cols wi-1, wi, wi+1
                u3[0] = vlo ? in[(size_t)((ho * 16 + wi - 1) * 8 + co) * NB2] : (f32x2)(0.f);
                u3[1] =       in[(size_t)((ho * 16 + wi    ) * 8 + co) * NB2];
                u3[2] = vhi ? in[(size_t)((ho * 16 + wi + 1) * 8 + co) * NB2] : (f32x2)(0.f);

                if (s >= 1 && s <= 4)      // ho is an owned row (compile-time)
                    pb += bco * u3[1];

                #pragma unroll
                for (int kh = 0; kh < 3; ++kh) {
                    const int m = s - 2 + kh;          // target owned row
                    if (m >= 0 && m <= 3) {            // compile-time filter
                        #pragma unroll
                        for (int ci = 0; ci < 8; ++ci)
                            #pragma unroll
                            for (int kw = 0; kw < 3; ++kw) {
                                const int idx = ci * 9 + kh * 3 + kw;
                                const float Kv = w[idx >> 2][idx & 3];
                                acc[m][ci] += Kv * u3[2 - kw];   // dw = 1-kw
                            }
                    }
                }
            }
        }
    }

    #pragma unroll
    for (int m = 0; m < 4; ++m)
        #pragma unroll
        for (int ci = 0; ci < 8; ++ci)
            wout[(size_t)(((r0 + m) * 16 + wi) * 8 + ci) * NB2] = acc[m][ci];

    // reduce bias partials across the 4 sub-waves (same k2, different wi)
    red[sub][kl] = pb;
    __syncthreads();
    if (sub == 0) {
        f32x2 tot = red[0][kl] + red[1][kl] + red[2][kl] + red[3][kl];
        float* bws = bias_ws + t * 8192 + b * 2048 + 2 * k2;
        atomicAdd(bws + 0, tot.x);
        atomicAdd(bws + 1, tot.y);
    }
}

// b_out_ = b_in + ws ; 16384 outputs (2 ul * 4 b * 2048 k)
__global__ void bias_finalize(const float* __restrict__ bu,
                              const float* __restrict__ bl,
                              const float* __restrict__ ws,
                              float* __restrict__ out)
{
    const int idx = blockIdx.x * blockDim.x + threadIdx.x;   // 0..16383
    const int ul  = idx >> 13;
    const int r   = idx & 8191;                              // b*2048 + k
    const float* bin = ul ? bl : bu;
    const size_t off = ul ? OFF_BL : OFF_BU;
    out[off + r] = bin[r] + ws[(size_t)ul * 8192 + r];
}

extern "C" void kernel_launch(void* const* d_in, const int* in_sizes, int n_in,
                              void* d_out, int out_size, void* d_ws, size_t ws_size,
                              hipStream_t stream) {
    // inputs: 0=x (unused), 1=kernel, 2=bias, 3=w_out_u, 4=b_out_u, 5=w_out_l, 6=b_out_l
    const float* kern = (const float*)d_in[1];
    const float* bias = (const float*)d_in[2];
    const float* wu   = (const float*)d_in[3];
    const float* bu   = (const float*)d_in[4];
    const float* wl   = (const float*)d_in[5];
    const float* bl   = (const float*)d_in[6];
    float* out = (float*)d_out;
    float* ws  = (float*)d_ws;

    // zero the 64 KB bias-partial region (graph replays re-run this node)
    (void)hipMemsetAsync(ws, 0, 2ull * 4 * NB * sizeof(float), stream);

    prep_kernel<<<9, 64, 0, stream>>>(kern, ws + WS_T);
    conv_back_kernel<<<dim3(2048), dim3(256), 0, stream>>>(wu, wl, ws + WS_T, bias, out, ws);
    bias_finalize<<<64, 256, 0, stream>>>(bu, bl, ws, out);
}

// Round 10
// 126.544 us; speedup vs baseline: 6.8017x; 5.5615x over previous
//
#include <hip/hip_runtime.h>

// Problem constants
#define NB    2048   // n_back (k)
#define NB2   1024   // NB/2 in f32x2 units
#define NOUT  2048   // H*W*COUT
#define NDIM  2048   // H*W*CIN

// Output flat offsets (floats) in d_out: [w_u_, b_u_, w_l_, b_l_]
#define OFF_BU  16777216ull
#define OFF_WL  16785408ull
#define OFF_BL  33562624ull

// ws layout (floats): [0,16384) bias partials (2,4,2048); [16384,16960) T
#define WS_T    16384

typedef float f32x2 __attribute__((ext_vector_type(2)));

// T[co*72 + ci*9 + kh*3 + kw] = kern[((kh*3+kw)*8+ci)*8+co]
// -> per co, 72 CONTIGUOUS floats: uniform-address loads of T become wide
// s_load_dwordx8/x16 batches into the SCALAR register file.
__global__ void prep_kernel(const float* __restrict__ kern, float* __restrict__ T) {
    const int i = blockIdx.x * 64 + threadIdx.x;   // 0..575
    if (i < 576) {
        const int kw = i % 3, kh = (i / 3) % 3, ci = (i / 9) % 8, co = i / 72;
        T[i] = kern[((kh * 3 + kw) * 8 + ci) * 8 + co];
    }
}

// co-outer rolling conv-backward, weights in SGPRs.
// Round-9 lesson: VGPR occupancy steps are 64/128/256 — a ~155-VGPR live set
// gets compiled to 84 VGPR + scratch spills (1.4 GB write traffic). Fix:
// weights are wave-uniform -> scalar file (separate budget). Per co
// iteration (forced rolled) only 72 SGPR weight values live; vector live
// set = acc[4][8] f32x2 (64) + u3 (6) + addressing ~ 90 <= 128 -> 4 w/SIMD.
__global__ __launch_bounds__(256, 4) void conv_back_kernel(
    const float* __restrict__ wu,
    const float* __restrict__ wl,
    const float* __restrict__ Tw,     // (8co, 72) transposed weights
    const float* __restrict__ bias,   // (8)
    float* __restrict__ outbuf,       // full d_out base
    float* __restrict__ bias_ws)      // (2,4,2048) partial bias sums
{
    const int bid = blockIdx.x;            // 0..2047
    const int klo = bid & 7;               // XCD id (k-disjoint partition)
    const int j   = bid >> 3;              // per-XCD order
    const int khi = j & 1;
    const int wig = (j >> 1) & 3;
    const int hq  = (j >> 3) & 3;
    const int sl  = j >> 5;                // 0..7
    const int t = sl >> 2, b = sl & 3;
    const int kc  = khi * 8 + klo;         // k chunk 0..15 (128 floats each)
    const int kl  = threadIdx.x & 63;
    const int sub = threadIdx.x >> 6;      // 0..3
    const int wi  = wig * 4 + sub;         // 0..15, wave-uniform
    const int r0  = hq * 4;                // first owned out row
    const int k2  = kc * 64 + kl;          // f32x2 index over k, 0..1023

    const f32x2* __restrict__ in =
        (const f32x2*)(t ? wl : wu) + (size_t)b * NOUT * NB2 + k2;
    f32x2* __restrict__ wout =
        (f32x2*)(outbuf + (t ? OFF_WL : 0)) + (size_t)b * NDIM * NB2 + k2;

    const bool vlo = wi > 0;               // wave-uniform edge masks
    const bool vhi = wi < 15;

    f32x2 acc[4][8];
    #pragma unroll
    for (int m = 0; m < 4; ++m)
        #pragma unroll
        for (int ci = 0; ci < 8; ++ci) acc[m][ci] = (f32x2)(0.f);
    f32x2 pb = (f32x2)(0.f);

    #pragma unroll 1
    for (int co = 0; co < 8; ++co) {
        const float* __restrict__ tb = Tw + co * 72;  // uniform -> s_loads
        const float bco = bias[co];

        #pragma unroll
        for (int s = 0; s < 6; ++s) {
            const int ho = r0 - 1 + s;     // current in-row
            if ((unsigned)ho < 16u) {      // block-uniform (edges of hq 0/3)
                f32x2 u3[3];               // cols wi-1, wi, wi+1
                u3[0] = vlo ? in[(size_t)((ho * 16 + wi - 1) * 8 + co) * NB2] : (f32x2)(0.f);
                u3[1] =       in[(size_t)((ho * 16 + wi    ) * 8 + co) * NB2];
                u3[2] = vhi ? in[(size_t)((ho * 16 + wi + 1) * 8 + co) * NB2] : (f32x2)(0.f);

                if (s >= 1 && s <= 4)      // ho is an owned row (compile-time)
                    pb += bco * u3[1];

                #pragma unroll
                for (int kh = 0; kh < 3; ++kh) {
                    const int m = s - 2 + kh;          // target owned row
                    if (m >= 0 && m <= 3) {            // compile-time filter
                        #pragma unroll
                        for (int ci = 0; ci < 8; ++ci)
                            #pragma unroll
                            for (int kw = 0; kw < 3; ++kw) {
                                const float Kv = tb[ci * 9 + kh * 3 + kw]; // SGPR
                                acc[m][ci] += Kv * u3[2 - kw];   // dw = 1-kw
                            }
                    }
                }
            }
        }
    }

    #pragma unroll
    for (int m = 0; m < 4; ++m)
        #pragma unroll
        for (int ci = 0; ci < 8; ++ci)
            wout[(size_t)(((r0 + m) * 16 + wi) * 8 + ci) * NB2] = acc[m][ci];

    // reduce bias partials across the 4 sub-waves (same k2, different wi)
    __shared__ f32x2 red[4][64];
    red[sub][kl] = pb;
    __syncthreads();
    if (sub == 0) {
        f32x2 tot = red[0][kl] + red[1][kl] + red[2][kl] + red[3][kl];
        float* bws = bias_ws + t * 8192 + b * 2048 + 2 * k2;
        atomicAdd(bws + 0, tot.x);
        atomicAdd(bws + 1, tot.y);
    }
}

// b_out_ = b_in + ws ; 16384 outputs (2 ul * 4 b * 2048 k)
__global__ void bias_finalize(const float* __restrict__ bu,
                              const float* __restrict__ bl,
                              const float* __restrict__ ws,
                              float* __restrict__ out)
{
    const int idx = blockIdx.x * blockDim.x + threadIdx.x;   // 0..16383
    const int ul  = idx >> 13;
    const int r   = idx & 8191;                              // b*2048 + k
    const float* bin = ul ? bl : bu;
    const size_t off = ul ? OFF_BL : OFF_BU;
    out[off + r] = bin[r] + ws[(size_t)ul * 8192 + r];
}

extern "C" void kernel_launch(void* const* d_in, const int* in_sizes, int n_in,
                              void* d_out, int out_size, void* d_ws, size_t ws_size,
                              hipStream_t stream) {
    // inputs: 0=x (unused), 1=kernel, 2=bias, 3=w_out_u, 4=b_out_u, 5=w_out_l, 6=b_out_l
    const float* kern = (const float*)d_in[1];
    const float* bias = (const float*)d_in[2];
    const float* wu   = (const float*)d_in[3];
    const float* bu   = (const float*)d_in[4];
    const float* wl   = (const float*)d_in[5];
    const float* bl   = (const float*)d_in[6];
    float* out = (float*)d_out;
    float* ws  = (float*)d_ws;

    // zero the 64 KB bias-partial region (graph replays re-run this node)
    (void)hipMemsetAsync(ws, 0, 2ull * 4 * NB * sizeof(float), stream);

    prep_kernel<<<9, 64, 0, stream>>>(kern, ws + WS_T);
    conv_back_kernel<<<dim3(2048), dim3(256), 0, stream>>>(wu, wl, ws + WS_T, bias, out, ws);
    bias_finalize<<<64, 256, 0, stream>>>(bu, bl, ws, out);
}

// Round 11
// 97.436 us; speedup vs baseline: 8.8337x; 1.2987x over previous
//
#include <hip/hip_runtime.h>

// Problem constants
#define NB    2048   // n_back (k)
#define NB4   512    // NB/4 in f32x4 units
#define NOUT  2048   // H*W*COUT
#define NDIM  2048   // H*W*CIN

// Output flat offsets (floats) in d_out: [w_u_, b_u_, w_l_, b_l_]
#define OFF_BU  16777216ull
#define OFF_WL  16785408ull
#define OFF_BL  33562624ull

// ws layout (floats): [0,16384) bias partials (2,4,2048); [16384,16960) T
#define WS_T    16384

typedef float f32x4 __attribute__((ext_vector_type(4)));

// T[co*72 + ci*9 + kh*3 + kw] = kern[((kh*3+kw)*8+ci)*8+co]
// -> per co, 72 CONTIGUOUS floats: uniform-address loads become wide
// s_load batches into the scalar register file (round-10 win: VGPR=60).
__global__ void prep_kernel(const float* __restrict__ kern, float* __restrict__ T) {
    const int i = blockIdx.x * 64 + threadIdx.x;   // 0..575
    if (i < 576) {
        const int kw = i % 3, kh = (i / 3) % 3, ci = (i / 9) % 8, co = i / 72;
        T[i] = kern[((kh * 3 + kw) * 8 + ci) * 8 + co];
    }
}

// co-outer conv-backward, f32x4 lanes, 2 owned rows/thread.
// Round-10 was VALU-issue-bound (64% busy, 142us, HBM 6%): per-output
// overhead ~ FMA work. This round: same 64 output floats/thread but
// f32x4-wide -> loads 144->96, stores 32->16, addr/select ops halved;
// f32x4 arith gives the backend v_pk_fma_f32 pairs.
// Weights stay in SGPRs (separate budget; VGPR cliff at 128 respected:
// acc 64 + u 12 + addr ~15 < 128 -> 4 waves/SIMD).
__global__ __launch_bounds__(256, 4) void conv_back_kernel(
    const float* __restrict__ wu,
    const float* __restrict__ wl,
    const float* __restrict__ Tw,     // (8co, 72) transposed weights
    const float* __restrict__ bias,   // (8)
    float* __restrict__ outbuf,       // full d_out base
    float* __restrict__ bias_ws)      // (2,4,2048) partial bias sums
{
    const int bid = blockIdx.x;            // 0..2047
    const int klo = bid & 7;               // XCD id = k-chunk (k-disjoint)
    const int j   = bid >> 3;              // per-XCD order
    const int wig = j & 3;                 // wi group
    const int hr  = (j >> 2) & 7;          // 2-row group
    const int sl  = j >> 5;                // 0..7 (t,b)
    const int t = sl >> 2, b = sl & 3;
    const int kl  = threadIdx.x & 63;
    const int sub = threadIdx.x >> 6;      // 0..3
    const int wi  = wig * 4 + sub;         // 0..15, wave-uniform
    const int r0  = hr * 2;                // first owned out row
    const int k4  = klo * 64 + kl;         // f32x4 index over k, 0..511

    const f32x4* __restrict__ in =
        (const f32x4*)(t ? wl : wu) + (size_t)b * NOUT * NB4 + k4;
    f32x4* __restrict__ wout =
        (f32x4*)(outbuf + (t ? OFF_WL : 0)) + (size_t)b * NDIM * NB4 + k4;

    const bool vlo = wi > 0;               // wave-uniform edge masks
    const bool vhi = wi < 15;

    f32x4 acc[2][8];
    #pragma unroll
    for (int m = 0; m < 2; ++m)
        #pragma unroll
        for (int ci = 0; ci < 8; ++ci) acc[m][ci] = (f32x4)(0.f);
    f32x4 pb = (f32x4)(0.f);

    #pragma unroll 1
    for (int co = 0; co < 8; ++co) {
        const float* __restrict__ tb = Tw + co * 72;  // uniform -> s_loads
        const float bco = bias[co];

        #pragma unroll
        for (int s = 0; s < 4; ++s) {
            const int ho = r0 - 1 + s;     // current in-row
            if ((unsigned)ho < 16u) {      // block-uniform (edges of hr 0/7)
                f32x4 u3[3];               // cols wi-1, wi, wi+1
                u3[0] = vlo ? in[(size_t)((ho * 16 + wi - 1) * 8 + co) * NB4] : (f32x4)(0.f);
                u3[1] =       in[(size_t)((ho * 16 + wi    ) * 8 + co) * NB4];
                u3[2] = vhi ? in[(size_t)((ho * 16 + wi + 1) * 8 + co) * NB4] : (f32x4)(0.f);

                if (s == 1 || s == 2)      // ho is an owned row (compile-time)
                    pb += bco * u3[1];

                #pragma unroll
                for (int kh = 0; kh < 3; ++kh) {
                    const int m = s - 2 + kh;          // target owned row
                    if (m >= 0 && m <= 1) {            // compile-time filter
                        #pragma unroll
                        for (int ci = 0; ci < 8; ++ci)
                            #pragma unroll
                            for (int kw = 0; kw < 3; ++kw) {
                                const float Kv = tb[ci * 9 + kh * 3 + kw]; // SGPR
                                acc[m][ci] += Kv * u3[2 - kw];   // dw = 1-kw
                            }
                    }
                }
            }
        }
    }

    #pragma unroll
    for (int m = 0; m < 2; ++m)
        #pragma unroll
        for (int ci = 0; ci < 8; ++ci)
            wout[(size_t)(((r0 + m) * 16 + wi) * 8 + ci) * NB4] = acc[m][ci];

    // reduce bias partials across the 4 sub-waves (same k4, different wi)
    __shared__ f32x4 red[4][64];
    red[sub][kl] = pb;
    __syncthreads();
    if (sub == 0) {
        f32x4 tot = red[0][kl] + red[1][kl] + red[2][kl] + red[3][kl];
        float* bws = bias_ws + t * 8192 + b * 2048 + 4 * k4;
        atomicAdd(bws + 0, tot.x);
        atomicAdd(bws + 1, tot.y);
        atomicAdd(bws + 2, tot.z);
        atomicAdd(bws + 3, tot.w);
    }
}

// b_out_ = b_in + ws ; 16384 outputs (2 ul * 4 b * 2048 k)
__global__ void bias_finalize(const float* __restrict__ bu,
                              const float* __restrict__ bl,
                              const float* __restrict__ ws,
                              float* __restrict__ out)
{
    const int idx = blockIdx.x * blockDim.x + threadIdx.x;   // 0..16383
    const int ul  = idx >> 13;
    const int r   = idx & 8191;                              // b*2048 + k
    const float* bin = ul ? bl : bu;
    const size_t off = ul ? OFF_BL : OFF_BU;
    out[off + r] = bin[r] + ws[(size_t)ul * 8192 + r];
}

extern "C" void kernel_launch(void* const* d_in, const int* in_sizes, int n_in,
                              void* d_out, int out_size, void* d_ws, size_t ws_size,
                              hipStream_t stream) {
    // inputs: 0=x (unused), 1=kernel, 2=bias, 3=w_out_u, 4=b_out_u, 5=w_out_l, 6=b_out_l
    const float* kern = (const float*)d_in[1];
    const float* bias = (const float*)d_in[2];
    const float* wu   = (const float*)d_in[3];
    const float* bu   = (const float*)d_in[4];
    const float* wl   = (const float*)d_in[5];
    const float* bl   = (const float*)d_in[6];
    float* out = (float*)d_out;
    float* ws  = (float*)d_ws;

    // zero the 64 KB bias-partial region (graph replays re-run this node)
    (void)hipMemsetAsync(ws, 0, 2ull * 4 * NB * sizeof(float), stream);

    prep_kernel<<<9, 64, 0, stream>>>(kern, ws + WS_T);
    conv_back_kernel<<<dim3(2048), dim3(256), 0, stream>>>(wu, wl, ws + WS_T, bias, out, ws);
    bias_finalize<<<64, 256, 0, stream>>>(bu, bl, ws, out);
}